// Round 1
// baseline (123.651 us; speedup 1.0000x reference)
//
#include <hip/hip_runtime.h>
#include <cmath>

#define NPIX   289          // 17*17
#define NU     10           // unique GLCM offsets (12 slots, 2 dups)
#define NF     70           // 4 stat + 6 hist + 60 glcm
#define NWX    60
#define IMG_W  256
#define IMG_HW 65536
#define NWIN   28800        // 8 * 60 * 60
#define ACC    560          // BATCH * NF
#define WPB    4            // waves (windows) per block
#define NBLK   (NWIN / WPB) // 7200

// slot -> unique offset index for the 12 reference offsets
__device__ __constant__ int c_s2u[12] = {0,1,2,3,4,1,5,3,6,7,8,9};

// unique offsets (dr, dc); flat-shift joff = dr*17 + dc
constexpr int DRu[NU] = {0, 1, 1, 1, 0, 2, 0, 2, 3, 2};
constexpr int DCu[NU] = {1, 1, 0,-1, 2, 0, 3, 2, 0,-2};
constexpr int JOFF[NU] = {1, 18, 17, 16, 2, 34, 3, 36, 51, 32};
// 1/(2*npairs), npairs = (17-dr)*(17-|dc|)
constexpr float INV2N[NU] = {1.f/544.f, 1.f/512.f, 1.f/544.f, 1.f/512.f, 1.f/510.f,
                             1.f/510.f, 1.f/476.f, 1.f/450.f, 1.f/476.f, 1.f/450.f};

// column-validity masks per distinct dc: bit t set iff target column constraint holds.
// dc>0: col(t) >= dc ; dc<0: col(t) <= 16+dc. Row overflow self-masks (padded words),
// word 9 (only bit = pixel (16,16), never a valid SOURCE) is skipped in the count loop.
struct CMs { unsigned m[10]; };
constexpr CMs mkcm(int dc) {
    CMs c{};
    for (int t = 0; t < NPIX; ++t) {
        int col = t % 17;
        bool ok = (dc > 0) ? (col >= dc) : (col <= 16 + dc);
        if (ok) c.m[t >> 5] |= 1u << (t & 31);
    }
    return c;
}
constexpr CMs CMp1 = mkcm(1), CMp2 = mkcm(2), CMp3 = mkcm(3);
constexpr CMs CMn1 = mkcm(-1), CMn2 = mkcm(-2);

// fused per-element constants for the upper-triangle feature pass.
// entry order == idx28(a,b) = 8*(a-1) - a*(a-1)/2 + (b-a), a<=b in 1..7
struct alignas(32) FtE { float w, d2, inv, si, sii, sij, q0, q1; };
struct FtTab { FtE e[28]; };
constexpr FtTab mkft() {
    FtTab t{};
    int n = 0;
    for (int a = 1; a <= 7; ++a)
        for (int b = a; b <= 7; ++b) {
            int i = a - 1, j = b - 1;
            float w  = (a == b) ? 1.f : 2.f;
            float d2 = (float)((i - j) * (i - j));
            t.e[n] = FtE{w, d2, 1.f / (1.f + d2),
                         0.5f * (float)(i + j),
                         0.5f * (float)(i * i + j * j),
                         (float)(i * j), 0.f, 0.f};
            ++n;
        }
    return t;
}
__device__ __constant__ FtTab c_ft = mkft();

// GLCM pair count for one offset: popc(ma & (mbMasked >> joff)), words 0..8.
template<int O>
__device__ __forceinline__ int gcnt(const unsigned* M, const unsigned* ma) {
    constexpr int wq = JOFF[O] >> 5;
    constexpr int rr = JOFF[O] & 31;
    int acc = 0;
#pragma unroll
    for (int w = 0; w < 9; ++w) {
        unsigned sh = (rr == 0) ? M[w + wq]
                    : __builtin_amdgcn_alignbit(M[w + wq + 1], M[w + wq], rr);
        acc += __popc(ma[w] & sh);
    }
    return acc;
}

__device__ __forceinline__ float wsum(float v){ for(int o=32;o;o>>=1) v += __shfl_xor(v,o,64); return v; }
__device__ __forceinline__ float wmax(float v){ for(int o=32;o;o>>=1) v = fmaxf(v,__shfl_xor(v,o,64)); return v; }
__device__ __forceinline__ float wmin(float v){ for(int o=32;o;o>>=1) v = fminf(v,__shfl_xor(v,o,64)); return v; }

// __launch_bounds__(256, 4): allow up to 128 VGPRs so the 22-dword bitmap state
// stays in arch VGPRs (VGPR_Count=20 previously => compiler was spilling).
__global__ __launch_bounds__(256, 4) void feat_kernel(const float* __restrict__ x,
                                                      float* __restrict__ ptot,
                                                      float* __restrict__ pnz,
                                                      int setmask) {
    __shared__ float s_g[WPB][NU * 28];
    __shared__ float s_uf[WPB][5][NU];
    __shared__ float s_s10[WPB][10];

    const int lane = threadIdx.x & 63;
    const int wid  = threadIdx.x >> 6;
    const int widx = blockIdx.x * WPB + wid;
    const int b    = widx / 3600;
    const int rem  = widx - b * 3600;
    const int wy   = rem / NWX;
    const int wx   = rem - wy * NWX;
    const float* img = x + (size_t)(b * 3 + 1) * IMG_HW + (wy * 4) * IMG_W + wx * 4;

    float* gl  = s_g[wid];
    float (*uf)[NU] = s_uf[wid];
    float* s10 = s_s10[wid];

    // lane -> (a,b) bin pair for the GLCM phase
    const int l49 = (lane < 49) ? lane : 48;
    const int ba  = l49 / 7 + 1;       // 1..7
    const int bb  = l49 - (ba - 1) * 7 + 1;
    // per-lane XOR masks: plane ^ xm == (bit set in bin index ? plane : ~plane)
    const unsigned long long xm0a = (ba & 1) ? 0ull : ~0ull;
    const unsigned long long xm1a = (ba & 2) ? 0ull : ~0ull;
    const unsigned long long xm2a = (ba & 4) ? 0ull : ~0ull;
    const unsigned long long xm0b = (bb & 1) ? 0ull : ~0ull;
    const unsigned long long xm1b = (bb & 2) ? 0ull : ~0ull;
    const unsigned long long xm2b = (bb & 4) ? 0ull : ~0ull;

    // ---- pass A: load, threshold, quantize, stats; ballots consumed per-k ----
    float lsum = 0.f, lss = 0.f, lmax = -1e30f, lmin = 1e30f;
    int n = 0, c1 = 0, c2 = 0, c3 = 0, c4 = 0, c5 = 0, c6 = 0;
    unsigned ma32[10], mb32[12];
#pragma unroll
    for (int k = 0; k < 5; ++k) {
        const int t = lane + k * 64;
        float val = 0.f;
        if (t < NPIX) {
            const int r = t / 17;
            float p = img[r * (IMG_W - 17) + t];   // r*256 + c == r*239 + t
            val = (p < 10.f) ? 0.f : p;
        }
        // quantize: val in {0} U [10,255] -> qq = min((int)(val/40 + 0.8125), 7); qq=0 iff val==0
        int qq = min((int)fmaf(val, 0.025f, 0.8125f), 7);
        // stats (nonzero-masked)
        lsum += val;
        float d = (val != 0.f) ? (val - 127.5f) : 0.f;
        lss = fmaf(d, d, lss);
        lmax = fmaxf(lmax, val);                          // zeros can't win (max>=10)
        lmin = fminf(lmin, (val != 0.f) ? val : 1e30f);
        // bit planes (wave-uniform) -- consumed immediately, not stored
        unsigned long long p0 = __ballot(qq & 1);
        unsigned long long p1 = __ballot(qq & 2);
        unsigned long long p2 = __ballot(qq & 4);
        // scalar-pipe histogram
        n  += __popcll(p0 | p1 | p2);
        c1 += __popcll(p0 & ~p1 & ~p2);
        c2 += __popcll(~p0 & p1 & ~p2);
        c3 += __popcll(p0 & p1 & ~p2);
        c4 += __popcll(~p0 & ~p1 & p2);
        c5 += __popcll(p0 & ~p1 & p2);
        c6 += __popcll(~p0 & p1 & p2);
        // per-lane bin bitmaps
        unsigned long long mA = (p0 ^ xm0a) & (p1 ^ xm1a) & (p2 ^ xm2a);
        unsigned long long mB = (p0 ^ xm0b) & (p1 ^ xm1b) & (p2 ^ xm2b);
        ma32[2*k]   = (unsigned)mA;  ma32[2*k+1] = (unsigned)(mA >> 32);
        mb32[2*k]   = (unsigned)mB;  mb32[2*k+1] = (unsigned)(mB >> 32);
    }
    mb32[10] = 0u; mb32[11] = 0u;

    if (n == 0) return;   // all-zero window contributes nothing (no barriers in this kernel)

    const float fn   = (float)n;
    const float sum  = wsum(lsum);
    const float ss   = wsum(lss);
    const float mx   = wmax(lmax);
    const float mn   = wmin(lmin);
    const float mean = sum / fn;
    const float mc   = mean - 127.5f;
    const float var  = fmaxf(ss / fn - mc * mc, 0.f);
    const float stdv = sqrtf(var);

    if (lane == 0) {
        s10[0] = mean;
        s10[1] = stdv;
        s10[2] = (mx - mean) / (stdv + 1e-9f);
        s10[3] = (mean - mn) / (stdv + 1e-9f);
        s10[4] = (float)c1 * (1.f / 289.f);
        s10[5] = (float)c2 * (1.f / 289.f);
        s10[6] = (float)c3 * (1.f / 289.f);
        s10[7] = (float)c4 * (1.f / 289.f);
        s10[8] = (float)c5 * (1.f / 289.f);
        s10[9] = (float)c6 * (1.f / 289.f);
    }

    // ---- GLCM counts: column-masked mb, shared per distinct dc ----
    int cnta[NU];
    {
        unsigned mv[12]; mv[10] = 0u; mv[11] = 0u;
        // dc == 0 offsets use mb32 directly
        cnta[2] = gcnt<2>(mb32, ma32);
        cnta[5] = gcnt<5>(mb32, ma32);
        cnta[8] = gcnt<8>(mb32, ma32);
#pragma unroll
        for (int w = 0; w < 10; ++w) mv[w] = mb32[w] & CMp1.m[w];
        cnta[0] = gcnt<0>(mv, ma32);
        cnta[1] = gcnt<1>(mv, ma32);
#pragma unroll
        for (int w = 0; w < 10; ++w) mv[w] = mb32[w] & CMp2.m[w];
        cnta[4] = gcnt<4>(mv, ma32);
        cnta[7] = gcnt<7>(mv, ma32);
#pragma unroll
        for (int w = 0; w < 10; ++w) mv[w] = mb32[w] & CMp3.m[w];
        cnta[6] = gcnt<6>(mv, ma32);
#pragma unroll
        for (int w = 0; w < 10; ++w) mv[w] = mb32[w] & CMn1.m[w];
        cnta[3] = gcnt<3>(mv, ma32);
#pragma unroll
        for (int w = 0; w < 10; ++w) mv[w] = mb32[w] & CMn2.m[w];
        cnta[9] = gcnt<9>(mv, ma32);
    }

    // ---- symmetrize via shuffle, stage UPPER TRIANGLE (28) into LDS ----
    const int partner = (bb - 1) * 7 + (ba - 1);   // transpose lane within 49
    const int amin  = min(ba, bb);
    const int idx28 = 8 * (amin - 1) - ((amin * (amin - 1)) >> 1) + (max(ba, bb) - amin);
    const bool wr   = (lane < 49) && (ba <= bb);
#pragma unroll
    for (int o = 0; o < NU; ++o) {
        int pc = __shfl(cnta[o], partner, 64);
        float g = (float)(cnta[o] + pc) * INV2N[o];
        if (wr) gl[o * 28 + idx28] = g;
    }

    // ---- features over upper triangle: 4 sub-lanes per offset, 7 iters ----
    const int fo  = lane & 15;   // offset (active fo<10)
    const int sub = lane >> 4;   // 0..3
    float gsum=0.f, entU=0.f, conU=0.f, homU=0.f, g2=0.f, siU=0.f, siiU=0.f, sijU=0.f;
    if (fo < NU) {
#pragma unroll
        for (int i = 0; i < 7; ++i) {
            const int e = sub + 4 * i;           // 0..27, exact partition
            FtE c = c_ft.e[e];                   // cached vmem loads (idle pipe)
            float g  = gl[fo * 28 + e];
            float gw = g * c.w;                  // weight 1 (diag) / 2 (off-diag)
            float l  = __log2f(g + 1e-8f);
            gsum += gw;
            entU  = fmaf(gw, l,      entU);
            conU  = fmaf(gw, c.d2,   conU);
            homU  = fmaf(gw, c.inv,  homU);
            g2    = fmaf(gw, g,      g2);
            siU   = fmaf(gw, c.si,   siU);
            siiU  = fmaf(gw, c.sii,  siiU);
            sijU  = fmaf(gw, c.sij,  sijU);
        }
    }
#pragma unroll
    for (int s = 16; s <= 32; s <<= 1) {
        gsum += __shfl_xor(gsum, s, 64);  entU += __shfl_xor(entU, s, 64);
        conU += __shfl_xor(conU, s, 64);  homU += __shfl_xor(homU, s, 64);
        g2   += __shfl_xor(g2,   s, 64);  siU  += __shfl_xor(siU,  s, 64);
        siiU += __shfl_xor(siiU, s, 64);  sijU += __shfl_xor(sijU, s, 64);
    }
    if (fo < NU && sub == 0) {
        const float invg = 1.f / fmaxf(gsum, 1e-12f);
        const float si  = siU  * invg;
        const float sii = siiU * invg;
        const float sij = sijU * invg;
        const float varg = fmaxf(sii - si * si, 0.f);   // == sdi*sdj (symmetric P)
        const float cov  = sij - si * si;
        uf[0][fo] = conU * invg;
        uf[1][fo] = homU * invg;
        uf[2][fo] = sqrtf(g2) * invg;
        uf[3][fo] = (varg < 1e-15f) ? 1.f : cov / fmaxf(varg, 1e-15f);
        uf[4][fo] = -entU;
    }

    // ---- accumulate into partial sets ----
    const int setbase = (widx & setmask) * ACC;
    const int obase   = b * NF;
    for (int t = lane; t < NF; t += 64) {
        float f;
        if (t < 10) {
            f = s10[t];
        } else {
            int u    = t - 10;
            int grp  = u / 12;          // 0=contrast 1=homog 2=energy 3=corr 4=entropy
            int slot = u - grp * 12;
            f = uf[grp][c_s2u[slot]];
        }
        if (f != 0.f) {
            atomicAdd(&ptot[setbase + obase + t], f);
            atomicAdd(&pnz[setbase + obase + t], 1.f);
        }
    }
}

__global__ void reduce_kernel(const float* __restrict__ ptot,
                              const float* __restrict__ pnz,
                              float* __restrict__ out, int nset) {
    int t = blockIdx.x * blockDim.x + threadIdx.x;
    if (t >= ACC) return;
    float s = 0.f, nz = 0.f;
    for (int k = 0; k < nset; ++k) {
        s  += ptot[(size_t)k * ACC + t];
        nz += pnz[(size_t)k * ACC + t];
    }
    out[t] = s / (nz + 1e-9f);
}

extern "C" void kernel_launch(void* const* d_in, const int* in_sizes, int n_in,
                              void* d_out, int out_size, void* d_ws, size_t ws_size,
                              hipStream_t stream) {
    (void)in_sizes; (void)n_in; (void)out_size;
    const float* x = (const float*)d_in[0];
    float* out = (float*)d_out;

    const size_t per_set = (size_t)2 * ACC * sizeof(float);   // 4480 B
    int maxs = (ws_size >= per_set) ? (int)(ws_size / per_set) : 1;
    int nset = 1;
    while ((nset * 2) <= maxs && nset < 64) nset <<= 1;

    float* ptot = (float*)d_ws;
    float* pnz  = ptot + (size_t)nset * ACC;

    hipMemsetAsync(d_ws, 0, (size_t)nset * per_set, stream);
    feat_kernel<<<dim3(NBLK), dim3(256), 0, stream>>>(x, ptot, pnz, nset - 1);
    reduce_kernel<<<dim3((ACC + 255) / 256), dim3(256), 0, stream>>>(ptot, pnz, out, nset);
}

// Round 2
// 120.358 us; speedup vs baseline: 1.0274x; 1.0274x over previous
//
#include <hip/hip_runtime.h>
#include <cmath>

#define NPIX   289          // 17*17
#define NU     10           // unique GLCM offsets (12 slots, 2 dups)
#define NF     70           // 4 stat + 6 hist + 60 glcm
#define NWX    60
#define IMG_W  256
#define IMG_HW 65536
#define NWIN   28800        // 8 * 60 * 60
#define ACC    560          // BATCH * NF
#define WPB    4            // waves (windows) per block
#define NBLK   (NWIN / WPB) // 7200
#define GLS    29           // padded LDS stride for 28-entry GLCM triangles (bank spread)

// slot -> unique offset index for the 12 reference offsets
__device__ __constant__ int c_s2u[12] = {0,1,2,3,4,1,5,3,6,7,8,9};

// unique offsets (dr, dc); flat-shift joff = dr*17 + dc
constexpr int JOFF[NU] = {1, 18, 17, 16, 2, 34, 3, 36, 51, 32};
// 1/(2*npairs), npairs = (17-dr)*(17-|dc|)
constexpr float INV2N[NU] = {1.f/544.f, 1.f/512.f, 1.f/544.f, 1.f/512.f, 1.f/510.f,
                             1.f/510.f, 1.f/476.f, 1.f/450.f, 1.f/476.f, 1.f/450.f};

// column-validity masks per distinct dc: bit t set iff target column constraint holds.
// dc>0: col(t) >= dc ; dc<0: col(t) <= 16+dc. Row overflow self-masks (shift past bit 288).
struct CMs { unsigned m[10]; };
constexpr CMs mkcm(int dc) {
    CMs c{};
    for (int t = 0; t < NPIX; ++t) {
        int col = t % 17;
        bool ok = (dc > 0) ? (col >= dc) : (col <= 16 + dc);
        if (ok) c.m[t >> 5] |= 1u << (t & 31);
    }
    return c;
}
constexpr CMs CMp1 = mkcm(1), CMp2 = mkcm(2), CMp3 = mkcm(3);
constexpr CMs CMn1 = mkcm(-1), CMn2 = mkcm(-2);

// fused per-element constants for the upper-triangle feature pass.
// entry order == idx28(a,b) = 8*(a-1) - a*(a-1)/2 + (b-a), a<=b in 1..7
struct alignas(32) FtE { float w, d2, inv, si, sii, sij, q0, q1; };
struct FtTab { FtE e[28]; };
constexpr FtTab mkft() {
    FtTab t{};
    int n = 0;
    for (int a = 1; a <= 7; ++a)
        for (int b = a; b <= 7; ++b) {
            int i = a - 1, j = b - 1;
            float w  = (a == b) ? 1.f : 2.f;
            float d2 = (float)((i - j) * (i - j));
            t.e[n] = FtE{w, d2, 1.f / (1.f + d2),
                         0.5f * (float)(i + j),
                         0.5f * (float)(i * i + j * j),
                         (float)(i * j), 0.f, 0.f};
            ++n;
        }
    return t;
}
__device__ __constant__ FtTab c_ft = mkft();

// GLCM pair count for one offset: popc(ma & shifted(mv)).
// nw prunes words whose sources all shift past bit 288 (offsets 5/7/8 -> 8 words),
// which also guarantees w+wq+1 <= 9 (no zero-padding words needed).
template<int O>
__device__ __forceinline__ int gcnt(const unsigned* __restrict__ M,
                                    const unsigned* __restrict__ ma) {
    constexpr int wq = JOFF[O] >> 5;
    constexpr int rr = JOFF[O] & 31;
    constexpr int nw = (288 - JOFF[O]) / 32 + 1;
    int acc = 0;
#pragma unroll
    for (int w = 0; w < nw; ++w) {
        unsigned sh = (rr == 0) ? M[w + wq]
                                : __builtin_amdgcn_alignbit(M[w + wq + 1], M[w + wq], rr);
        acc += __popc(ma[w] & sh);
    }
    return acc;
}

// ---- DPP wave-64 reductions: 6 VALU ops, no LDS pipe, result uniform via readlane ----
// update_dpp(old, src, ctrl, row_mask, bank_mask, bound_ctrl=false): masked/invalid -> old.
#define DPP_F(oldv, srcv, ctrl, rm) \
    __int_as_float(__builtin_amdgcn_update_dpp((oldv), __float_as_int(srcv), (ctrl), (rm), 0xF, false))

__device__ __forceinline__ float dpp_wsum(float v) {
    v += DPP_F(0, v, 0x111, 0xF);   // row_shr:1
    v += DPP_F(0, v, 0x112, 0xF);   // row_shr:2
    v += DPP_F(0, v, 0x114, 0xF);   // row_shr:4
    v += DPP_F(0, v, 0x118, 0xF);   // row_shr:8  -> lane15 of each row = row sum
    v += DPP_F(0, v, 0x142, 0xA);   // row_bcast15 into rows 1,3
    v += DPP_F(0, v, 0x143, 0xC);   // row_bcast31 into rows 2,3 -> lane63 = total
    return __int_as_float(__builtin_amdgcn_readlane(__float_as_int(v), 63));
}
__device__ __forceinline__ float dpp_wmax(float v) {
    v = fmaxf(v, DPP_F(__float_as_int(v), v, 0x111, 0xF));
    v = fmaxf(v, DPP_F(__float_as_int(v), v, 0x112, 0xF));
    v = fmaxf(v, DPP_F(__float_as_int(v), v, 0x114, 0xF));
    v = fmaxf(v, DPP_F(__float_as_int(v), v, 0x118, 0xF));
    v = fmaxf(v, DPP_F(__float_as_int(v), v, 0x142, 0xA));
    v = fmaxf(v, DPP_F(__float_as_int(v), v, 0x143, 0xC));
    return __int_as_float(__builtin_amdgcn_readlane(__float_as_int(v), 63));
}
__device__ __forceinline__ float dpp_wmin(float v) {
    v = fminf(v, DPP_F(__float_as_int(v), v, 0x111, 0xF));
    v = fminf(v, DPP_F(__float_as_int(v), v, 0x112, 0xF));
    v = fminf(v, DPP_F(__float_as_int(v), v, 0x114, 0xF));
    v = fminf(v, DPP_F(__float_as_int(v), v, 0x118, 0xF));
    v = fminf(v, DPP_F(__float_as_int(v), v, 0x142, 0xA));
    v = fminf(v, DPP_F(__float_as_int(v), v, 0x143, 0xC));
    return __int_as_float(__builtin_amdgcn_readlane(__float_as_int(v), 63));
}

__device__ __forceinline__ float bperm_f(int addr, float v) {
    return __int_as_float(__builtin_amdgcn_ds_bpermute(addr, __float_as_int(v)));
}

__global__ __launch_bounds__(256, 4) void feat_kernel(const float* __restrict__ x,
                                                      float* __restrict__ ptot,
                                                      float* __restrict__ pnz,
                                                      int setmask) {
    __shared__ float s_g[WPB][NU * GLS];
    __shared__ float s_uf[WPB][5][NU];
    __shared__ float s_s10[WPB][10];

    const int lane = threadIdx.x & 63;
    const int wid  = threadIdx.x >> 6;
    const int widx = blockIdx.x * WPB + wid;
    const int b    = widx / 3600;
    const int rem  = widx - b * 3600;
    const int wy   = rem / NWX;
    const int wx   = rem - wy * NWX;
    const float* img = x + (size_t)(b * 3 + 1) * IMG_HW + (wy * 4) * IMG_W + wx * 4;

    float* gl  = s_g[wid];
    float (*uf)[NU] = s_uf[wid];
    float* s10 = s_s10[wid];

    // lane -> (a,b) bin pair for the GLCM phase
    const int l49 = (lane < 49) ? lane : 48;
    const int ba  = l49 / 7 + 1;       // 1..7
    const int bb  = l49 - (ba - 1) * 7 + 1;
    const int partner = (bb - 1) * 7 + (ba - 1);   // lane holding (bb,ba); its mA == our mB
    const int paddr   = partner << 2;
    // per-lane XOR masks for mA only (mB comes from the partner lane via bpermute)
    const unsigned long long xm0a = (ba & 1) ? 0ull : ~0ull;
    const unsigned long long xm1a = (ba & 2) ? 0ull : ~0ull;
    const unsigned long long xm2a = (ba & 4) ? 0ull : ~0ull;

    // ---- pass A: load, threshold, quantize, stats; ballots consumed per-k ----
    float lsum = 0.f, lss = 0.f, lmax = -1e30f, lmin = 1e30f;
    int n = 0, c1 = 0, c2 = 0, c3 = 0, c4 = 0, c5 = 0, c6 = 0;
    unsigned ma32[10];
#pragma unroll
    for (int k = 0; k < 5; ++k) {
        const int t = lane + k * 64;
        float val;
        if (k < 4) {                                   // t <= 255 < NPIX always
            const int r = t / 17;
            float p = img[r * (IMG_W - 17) + t];       // r*256 + c == r*239 + t
            val = (p < 10.f) ? 0.f : p;
        } else {
            float p = 0.f;
            if (t < NPIX) {
                const int r = t / 17;
                p = img[r * (IMG_W - 17) + t];
            }
            val = (p < 10.f) ? 0.f : p;
        }
        // quantize: val in {0} U [10,255] -> qq = (int)(val/40 + 0.8125) in 0..7 (no clamp needed)
        int qq = (int)fmaf(val, 0.025f, 0.8125f);
        // stats (nonzero-masked)
        lsum += val;
        float d = (val != 0.f) ? (val - 127.5f) : 0.f;
        lss = fmaf(d, d, lss);
        lmax = fmaxf(lmax, val);                          // zeros can't win (max>=10)
        lmin = fminf(lmin, (val != 0.f) ? val : 1e30f);
        // bit planes (wave-uniform) -- consumed immediately, not stored
        unsigned long long p0 = __ballot(qq & 1);
        unsigned long long p1 = __ballot(qq & 2);
        unsigned long long p2 = __ballot(qq & 4);
        // scalar-pipe histogram
        n  += __popcll(p0 | p1 | p2);
        c1 += __popcll(p0 & ~p1 & ~p2);
        c2 += __popcll(~p0 & p1 & ~p2);
        c3 += __popcll(p0 & p1 & ~p2);
        c4 += __popcll(~p0 & ~p1 & p2);
        c5 += __popcll(p0 & ~p1 & p2);
        c6 += __popcll(~p0 & p1 & p2);
        // per-lane bin bitmap for bin ba only
        unsigned long long mA = (p0 ^ xm0a) & (p1 ^ xm1a) & (p2 ^ xm2a);
        ma32[2*k]   = (unsigned)mA;
        ma32[2*k+1] = (unsigned)(mA >> 32);
    }

    if (n == 0) return;   // all-zero window contributes nothing (no barriers in this kernel)

    // ---- issue mB fetch early (LDS pipe); latency hides under the DPP stat reductions ----
    unsigned mv0[10];
#pragma unroll
    for (int w = 0; w < 10; ++w)
        mv0[w] = (unsigned)__builtin_amdgcn_ds_bpermute(paddr, (int)ma32[w]);

    const float fn   = (float)n;
    const float sum  = dpp_wsum(lsum);
    const float ss   = dpp_wsum(lss);
    const float mx   = dpp_wmax(lmax);
    const float mn   = dpp_wmin(lmin);
    const float mean = sum / fn;
    const float mc   = mean - 127.5f;
    const float var  = fmaxf(ss / fn - mc * mc, 0.f);
    const float stdv = sqrtf(var);

    if (lane == 0) {
        s10[0] = mean;
        s10[1] = stdv;
        s10[2] = (mx - mean) / (stdv + 1e-9f);
        s10[3] = (mean - mn) / (stdv + 1e-9f);
        s10[4] = (float)c1 * (1.f / 289.f);
        s10[5] = (float)c2 * (1.f / 289.f);
        s10[6] = (float)c3 * (1.f / 289.f);
        s10[7] = (float)c4 * (1.f / 289.f);
        s10[8] = (float)c5 * (1.f / 289.f);
        s10[9] = (float)c6 * (1.f / 289.f);
    }

    // ---- GLCM counts: column-masked mv0, shared per distinct dc ----
    int cnta[NU];
    {
        // dc == 0 offsets use mv0 directly (also first users -> covers bpermute wait)
        cnta[2] = gcnt<2>(mv0, ma32);
        cnta[5] = gcnt<5>(mv0, ma32);
        cnta[8] = gcnt<8>(mv0, ma32);
        unsigned mv[10];
#pragma unroll
        for (int w = 0; w < 10; ++w) mv[w] = mv0[w] & CMp1.m[w];
        cnta[0] = gcnt<0>(mv, ma32);
        cnta[1] = gcnt<1>(mv, ma32);
#pragma unroll
        for (int w = 0; w < 10; ++w) mv[w] = mv0[w] & CMp2.m[w];
        cnta[4] = gcnt<4>(mv, ma32);
        cnta[7] = gcnt<7>(mv, ma32);
#pragma unroll
        for (int w = 0; w < 10; ++w) mv[w] = mv0[w] & CMp3.m[w];
        cnta[6] = gcnt<6>(mv, ma32);
#pragma unroll
        for (int w = 0; w < 10; ++w) mv[w] = mv0[w] & CMn1.m[w];
        cnta[3] = gcnt<3>(mv, ma32);
#pragma unroll
        for (int w = 0; w < 10; ++w) mv[w] = mv0[w] & CMn2.m[w];
        cnta[9] = gcnt<9>(mv, ma32);
    }

    // ---- symmetrize via bpermute (same partner addr), stage UPPER TRIANGLE into LDS ----
    const int amin  = min(ba, bb);
    const int idx28 = 8 * (amin - 1) - ((amin * (amin - 1)) >> 1) + (max(ba, bb) - amin);
    const bool wr   = (lane < 49) && (ba <= bb);
#pragma unroll
    for (int o = 0; o < NU; ++o) {
        int pc = __builtin_amdgcn_ds_bpermute(paddr, cnta[o]);
        float g = (float)(cnta[o] + pc) * INV2N[o];
        if (wr) gl[o * GLS + idx28] = g;
    }

    // ---- features over upper triangle: 4 sub-lanes per offset, 7 iters ----
    const int fo  = lane & 15;   // offset (active fo<10)
    const int sub = lane >> 4;   // 0..3
    float gsum=0.f, entU=0.f, conU=0.f, homU=0.f, g2=0.f, siU=0.f, siiU=0.f, sijU=0.f;
    if (fo < NU) {
#pragma unroll
        for (int i = 0; i < 7; ++i) {
            const int e = sub + 4 * i;           // 0..27, exact partition
            FtE c = c_ft.e[e];                   // cached vmem loads (idle pipe)
            float g  = gl[fo * GLS + e];
            float gw = g * c.w;                  // weight 1 (diag) / 2 (off-diag)
            float l  = __log2f(g + 1e-8f);
            gsum += gw;
            entU  = fmaf(gw, l,      entU);
            conU  = fmaf(gw, c.d2,   conU);
            homU  = fmaf(gw, c.inv,  homU);
            g2    = fmaf(gw, g,      g2);
            siU   = fmaf(gw, c.si,   siU);
            siiU  = fmaf(gw, c.sii,  siiU);
            sijU  = fmaf(gw, c.sij,  sijU);
        }
    }
    // reduce over sub (lanes ^16, ^32) with precomputed bpermute addresses
    const int xa16 = (lane ^ 16) << 2;
    const int xa32 = (lane ^ 32) << 2;
    gsum += bperm_f(xa16, gsum);  entU += bperm_f(xa16, entU);
    conU += bperm_f(xa16, conU);  homU += bperm_f(xa16, homU);
    g2   += bperm_f(xa16, g2);    siU  += bperm_f(xa16, siU);
    siiU += bperm_f(xa16, siiU);  sijU += bperm_f(xa16, sijU);
    gsum += bperm_f(xa32, gsum);  entU += bperm_f(xa32, entU);
    conU += bperm_f(xa32, conU);  homU += bperm_f(xa32, homU);
    g2   += bperm_f(xa32, g2);    siU  += bperm_f(xa32, siU);
    siiU += bperm_f(xa32, siiU);  sijU += bperm_f(xa32, sijU);

    if (fo < NU && sub == 0) {
        const float invg = 1.f / fmaxf(gsum, 1e-12f);
        const float si  = siU  * invg;
        const float sii = siiU * invg;
        const float sij = sijU * invg;
        const float varg = fmaxf(sii - si * si, 0.f);   // == sdi*sdj (symmetric P)
        const float cov  = sij - si * si;
        uf[0][fo] = conU * invg;
        uf[1][fo] = homU * invg;
        uf[2][fo] = sqrtf(g2) * invg;
        uf[3][fo] = (varg < 1e-15f) ? 1.f : cov / fmaxf(varg, 1e-15f);
        uf[4][fo] = -entU;
    }

    // ---- accumulate into partial sets ----
    const int setbase = (widx & setmask) * ACC;
    const int obase   = b * NF;
    for (int t = lane; t < NF; t += 64) {
        float f;
        if (t < 10) {
            f = s10[t];
        } else {
            int u    = t - 10;
            int grp  = u / 12;          // 0=contrast 1=homog 2=energy 3=corr 4=entropy
            int slot = u - grp * 12;
            f = uf[grp][c_s2u[slot]];
        }
        if (f != 0.f) {
            atomicAdd(&ptot[setbase + obase + t], f);
            atomicAdd(&pnz[setbase + obase + t], 1.f);
        }
    }
}

__global__ void reduce_kernel(const float* __restrict__ ptot,
                              const float* __restrict__ pnz,
                              float* __restrict__ out, int nset) {
    int t = blockIdx.x * blockDim.x + threadIdx.x;
    if (t >= ACC) return;
    float s = 0.f, nz = 0.f;
    for (int k = 0; k < nset; ++k) {
        s  += ptot[(size_t)k * ACC + t];
        nz += pnz[(size_t)k * ACC + t];
    }
    out[t] = s / (nz + 1e-9f);
}

extern "C" void kernel_launch(void* const* d_in, const int* in_sizes, int n_in,
                              void* d_out, int out_size, void* d_ws, size_t ws_size,
                              hipStream_t stream) {
    (void)in_sizes; (void)n_in; (void)out_size;
    const float* x = (const float*)d_in[0];
    float* out = (float*)d_out;

    const size_t per_set = (size_t)2 * ACC * sizeof(float);   // 4480 B
    int maxs = (ws_size >= per_set) ? (int)(ws_size / per_set) : 1;
    int nset = 1;
    while ((nset * 2) <= maxs && nset < 64) nset <<= 1;

    float* ptot = (float*)d_ws;
    float* pnz  = ptot + (size_t)nset * ACC;

    hipMemsetAsync(d_ws, 0, (size_t)nset * per_set, stream);
    feat_kernel<<<dim3(NBLK), dim3(256), 0, stream>>>(x, ptot, pnz, nset - 1);
    reduce_kernel<<<dim3((ACC + 255) / 256), dim3(256), 0, stream>>>(ptot, pnz, out, nset);
}

// Round 3
// 113.700 us; speedup vs baseline: 1.0875x; 1.0586x over previous
//
#include <hip/hip_runtime.h>
#include <cmath>

#define NPIX   289          // 17*17
#define NU     10           // unique GLCM offsets (12 slots, 2 dups)
#define NF     70           // 4 stat + 6 hist + 60 glcm
#define NWX    60
#define IMG_W  256
#define IMG_HW 65536
#define NWIN   28800        // 8 * 60 * 60
#define ACC    560          // BATCH * NF
#define WPB    2            // waves (windows) per block (small blocks: less finish-skew per WG slot)
#define NBLK   (NWIN / WPB) // 14400
#define GLS    29           // padded LDS stride for 28-entry GLCM triangles (bank spread)

// slot -> unique offset index for the 12 reference offsets
__device__ __constant__ int c_s2u[12] = {0,1,2,3,4,1,5,3,6,7,8,9};

// unique offsets (dr, dc); flat-shift joff = dr*17 + dc
constexpr int JOFF[NU] = {1, 18, 17, 16, 2, 34, 3, 36, 51, 32};
// 1/(2*npairs), npairs = (17-dr)*(17-|dc|)
constexpr float INV2N[NU] = {1.f/544.f, 1.f/512.f, 1.f/544.f, 1.f/512.f, 1.f/510.f,
                             1.f/510.f, 1.f/476.f, 1.f/450.f, 1.f/476.f, 1.f/450.f};

// column-validity masks per distinct dc: bit t set iff target column constraint holds.
// dc>0: col(t) >= dc ; dc<0: col(t) <= 16+dc. Row overflow self-masks (shift past bit 288).
struct CMs { unsigned m[10]; };
constexpr CMs mkcm(int dc) {
    CMs c{};
    for (int t = 0; t < NPIX; ++t) {
        int col = t % 17;
        bool ok = (dc > 0) ? (col >= dc) : (col <= 16 + dc);
        if (ok) c.m[t >> 5] |= 1u << (t & 31);
    }
    return c;
}
constexpr CMs CMp1 = mkcm(1), CMp2 = mkcm(2), CMp3 = mkcm(3);
constexpr CMs CMn1 = mkcm(-1), CMn2 = mkcm(-2);

// fused per-element constants for the upper-triangle feature pass.
// entry order == idx28(a,b) = 8*(a-1) - a*(a-1)/2 + (b-a), a<=b in 1..7
struct alignas(32) FtE { float w, d2, inv, si, sii, sij, q0, q1; };
struct FtTab { FtE e[28]; };
constexpr FtTab mkft() {
    FtTab t{};
    int n = 0;
    for (int a = 1; a <= 7; ++a)
        for (int b = a; b <= 7; ++b) {
            int i = a - 1, j = b - 1;
            float w  = (a == b) ? 1.f : 2.f;
            float d2 = (float)((i - j) * (i - j));
            t.e[n] = FtE{w, d2, 1.f / (1.f + d2),
                         0.5f * (float)(i + j),
                         0.5f * (float)(i * i + j * j),
                         (float)(i * j), 0.f, 0.f};
            ++n;
        }
    return t;
}
__device__ __constant__ FtTab c_ft = mkft();

// GLCM pair count for one offset: popc(ma & shifted(mv)).
// nw prunes words whose sources all shift past bit 288 (offsets 5/7/8 -> 8 words),
// which also guarantees w+wq+1 <= 9 (no zero-padding words needed).
template<int O>
__device__ __forceinline__ int gcnt(const unsigned* __restrict__ M,
                                    const unsigned* __restrict__ ma) {
    constexpr int wq = JOFF[O] >> 5;
    constexpr int rr = JOFF[O] & 31;
    constexpr int nw = (288 - JOFF[O]) / 32 + 1;
    int acc = 0;
#pragma unroll
    for (int w = 0; w < nw; ++w) {
        unsigned sh = (rr == 0) ? M[w + wq]
                                : __builtin_amdgcn_alignbit(M[w + wq + 1], M[w + wq], rr);
        acc += __popc(ma[w] & sh);
    }
    return acc;
}

// ---- DPP wave-64 reductions: 6 VALU ops, no LDS pipe, result uniform via readlane ----
#define DPP_F(oldv, srcv, ctrl, rm) \
    __int_as_float(__builtin_amdgcn_update_dpp((oldv), __float_as_int(srcv), (ctrl), (rm), 0xF, false))

__device__ __forceinline__ float dpp_wsum(float v) {
    v += DPP_F(0, v, 0x111, 0xF);   // row_shr:1
    v += DPP_F(0, v, 0x112, 0xF);   // row_shr:2
    v += DPP_F(0, v, 0x114, 0xF);   // row_shr:4
    v += DPP_F(0, v, 0x118, 0xF);   // row_shr:8  -> lane15 of each row = row sum
    v += DPP_F(0, v, 0x142, 0xA);   // row_bcast15 into rows 1,3
    v += DPP_F(0, v, 0x143, 0xC);   // row_bcast31 into rows 2,3 -> lane63 = total
    return __int_as_float(__builtin_amdgcn_readlane(__float_as_int(v), 63));
}
__device__ __forceinline__ float dpp_wmax(float v) {
    v = fmaxf(v, DPP_F(__float_as_int(v), v, 0x111, 0xF));
    v = fmaxf(v, DPP_F(__float_as_int(v), v, 0x112, 0xF));
    v = fmaxf(v, DPP_F(__float_as_int(v), v, 0x114, 0xF));
    v = fmaxf(v, DPP_F(__float_as_int(v), v, 0x118, 0xF));
    v = fmaxf(v, DPP_F(__float_as_int(v), v, 0x142, 0xA));
    v = fmaxf(v, DPP_F(__float_as_int(v), v, 0x143, 0xC));
    return __int_as_float(__builtin_amdgcn_readlane(__float_as_int(v), 63));
}
__device__ __forceinline__ float dpp_wmin(float v) {
    v = fminf(v, DPP_F(__float_as_int(v), v, 0x111, 0xF));
    v = fminf(v, DPP_F(__float_as_int(v), v, 0x112, 0xF));
    v = fminf(v, DPP_F(__float_as_int(v), v, 0x114, 0xF));
    v = fminf(v, DPP_F(__float_as_int(v), v, 0x118, 0xF));
    v = fminf(v, DPP_F(__float_as_int(v), v, 0x142, 0xA));
    v = fminf(v, DPP_F(__float_as_int(v), v, 0x143, 0xC));
    return __int_as_float(__builtin_amdgcn_readlane(__float_as_int(v), 63));
}

__device__ __forceinline__ float bperm_f(int addr, float v) {
    return __int_as_float(__builtin_amdgcn_ds_bpermute(addr, __float_as_int(v)));
}

__global__ __launch_bounds__(128, 8) void feat_kernel(const float* __restrict__ x,
                                                      float* __restrict__ ptot,
                                                      float* __restrict__ pnz,
                                                      int setmask) {
    __shared__ float s_g[WPB][NU * GLS];
    __shared__ float s_uf[WPB][5][NU];
    __shared__ float s_s10[WPB][10];

    const int lane = threadIdx.x & 63;
    const int wid  = threadIdx.x >> 6;
    const int widx = blockIdx.x * WPB + wid;
    const int b    = widx / 3600;
    const int rem  = widx - b * 3600;
    const int wy   = rem / NWX;
    const int wx   = rem - wy * NWX;
    const float* img = x + (size_t)(b * 3 + 1) * IMG_HW + (wy * 4) * IMG_W + wx * 4;

    float* gl  = s_g[wid];
    float (*uf)[NU] = s_uf[wid];
    float* s10 = s_s10[wid];

    // lane -> (a,b) bin pair for the GLCM phase
    const int l49 = (lane < 49) ? lane : 48;
    const int ba  = l49 / 7 + 1;       // 1..7
    const int bb  = l49 - (ba - 1) * 7 + 1;
    const int partner = (bb - 1) * 7 + (ba - 1);   // lane holding (bb,ba); its mA == our mB
    const int paddr   = partner << 2;
    // per-lane XOR masks for mA only (mB comes from the partner lane via bpermute)
    const unsigned long long xm0a = (ba & 1) ? 0ull : ~0ull;
    const unsigned long long xm1a = (ba & 2) ? 0ull : ~0ull;
    const unsigned long long xm2a = (ba & 4) ? 0ull : ~0ull;

    // ---- pass A: load, threshold, quantize, stats; ballots consumed per-k ----
    float lsum = 0.f, lss = 0.f, lmax = -1e30f, lmin = 1e30f;
    int n = 0, c1 = 0, c2 = 0, c3 = 0, c4 = 0, c5 = 0, c6 = 0;
    unsigned ma32[10];
#pragma unroll
    for (int k = 0; k < 5; ++k) {
        const int t = lane + k * 64;
        float val;
        if (k < 4) {                                   // t <= 255 < NPIX always
            const int r = t / 17;
            float p = img[r * (IMG_W - 17) + t];       // r*256 + c == r*239 + t
            val = (p < 10.f) ? 0.f : p;
        } else {
            float p = 0.f;
            if (t < NPIX) {
                const int r = t / 17;
                p = img[r * (IMG_W - 17) + t];
            }
            val = (p < 10.f) ? 0.f : p;
        }
        // quantize: val in {0} U [10,255] -> qq = (int)(val/40 + 0.8125) in 0..7
        int qq = (int)fmaf(val, 0.025f, 0.8125f);
        // stats (nonzero-masked)
        lsum += val;
        float d = (val != 0.f) ? (val - 127.5f) : 0.f;
        lss = fmaf(d, d, lss);
        lmax = fmaxf(lmax, val);                          // zeros can't win (max>=10)
        lmin = fminf(lmin, (val != 0.f) ? val : 1e30f);
        // bit planes (wave-uniform) -- consumed immediately, not stored
        unsigned long long p0 = __ballot(qq & 1);
        unsigned long long p1 = __ballot(qq & 2);
        unsigned long long p2 = __ballot(qq & 4);
        // scalar-pipe histogram
        n  += __popcll(p0 | p1 | p2);
        c1 += __popcll(p0 & ~p1 & ~p2);
        c2 += __popcll(~p0 & p1 & ~p2);
        c3 += __popcll(p0 & p1 & ~p2);
        c4 += __popcll(~p0 & ~p1 & p2);
        c5 += __popcll(p0 & ~p1 & p2);
        c6 += __popcll(~p0 & p1 & p2);
        // per-lane bin bitmap for bin ba only
        unsigned long long mA = (p0 ^ xm0a) & (p1 ^ xm1a) & (p2 ^ xm2a);
        ma32[2*k]   = (unsigned)mA;
        ma32[2*k+1] = (unsigned)(mA >> 32);
    }

    if (n == 0) return;   // all-zero window contributes nothing (no barriers in this kernel)

    // ---- issue mB fetch early (LDS pipe); latency hides under the DPP stat reductions ----
    unsigned mv0[10];
#pragma unroll
    for (int w = 0; w < 10; ++w)
        mv0[w] = (unsigned)__builtin_amdgcn_ds_bpermute(paddr, (int)ma32[w]);

    const float fn   = (float)n;
    const float sum  = dpp_wsum(lsum);
    const float ss   = dpp_wsum(lss);
    const float mx   = dpp_wmax(lmax);
    const float mn   = dpp_wmin(lmin);
    const float mean = sum / fn;
    const float mc   = mean - 127.5f;
    const float var  = fmaxf(ss / fn - mc * mc, 0.f);
    const float stdv = sqrtf(var);

    if (lane == 0) {
        s10[0] = mean;
        s10[1] = stdv;
        s10[2] = (mx - mean) / (stdv + 1e-9f);
        s10[3] = (mean - mn) / (stdv + 1e-9f);
        s10[4] = (float)c1 * (1.f / 289.f);
        s10[5] = (float)c2 * (1.f / 289.f);
        s10[6] = (float)c3 * (1.f / 289.f);
        s10[7] = (float)c4 * (1.f / 289.f);
        s10[8] = (float)c5 * (1.f / 289.f);
        s10[9] = (float)c6 * (1.f / 289.f);
    }

    // ---- GLCM counts: column-masked mv0, shared per distinct dc ----
    int cnta[NU];
    {
        // dc == 0 offsets use mv0 directly (also first users -> covers bpermute wait)
        cnta[2] = gcnt<2>(mv0, ma32);
        cnta[5] = gcnt<5>(mv0, ma32);
        cnta[8] = gcnt<8>(mv0, ma32);
        unsigned mv[10];
#pragma unroll
        for (int w = 0; w < 10; ++w) mv[w] = mv0[w] & CMp1.m[w];
        cnta[0] = gcnt<0>(mv, ma32);
        cnta[1] = gcnt<1>(mv, ma32);
#pragma unroll
        for (int w = 0; w < 10; ++w) mv[w] = mv0[w] & CMp2.m[w];
        cnta[4] = gcnt<4>(mv, ma32);
        cnta[7] = gcnt<7>(mv, ma32);
#pragma unroll
        for (int w = 0; w < 10; ++w) mv[w] = mv0[w] & CMp3.m[w];
        cnta[6] = gcnt<6>(mv, ma32);
#pragma unroll
        for (int w = 0; w < 10; ++w) mv[w] = mv0[w] & CMn1.m[w];
        cnta[3] = gcnt<3>(mv, ma32);
#pragma unroll
        for (int w = 0; w < 10; ++w) mv[w] = mv0[w] & CMn2.m[w];
        cnta[9] = gcnt<9>(mv, ma32);
    }

    // ---- symmetrize via bpermute (same partner addr), stage UPPER TRIANGLE into LDS ----
    const int amin  = min(ba, bb);
    const int idx28 = 8 * (amin - 1) - ((amin * (amin - 1)) >> 1) + (max(ba, bb) - amin);
    const bool wr   = (lane < 49) && (ba <= bb);
#pragma unroll
    for (int o = 0; o < NU; ++o) {
        int pc = __builtin_amdgcn_ds_bpermute(paddr, cnta[o]);
        float g = (float)(cnta[o] + pc) * INV2N[o];
        if (wr) gl[o * GLS + idx28] = g;
    }

    // ---- features over upper triangle: 4 sub-lanes per offset, 7 iters ----
    const int fo  = lane & 15;   // offset (active fo<10)
    const int sub = lane >> 4;   // 0..3
    float gsum=0.f, entU=0.f, conU=0.f, homU=0.f, g2=0.f, siU=0.f, siiU=0.f, sijU=0.f;
    if (fo < NU) {
#pragma unroll
        for (int i = 0; i < 7; ++i) {
            const int e = sub + 4 * i;           // 0..27, exact partition
            FtE c = c_ft.e[e];                   // cached vmem loads (idle pipe)
            float g  = gl[fo * GLS + e];
            float gw = g * c.w;                  // weight 1 (diag) / 2 (off-diag)
            float l  = __log2f(g + 1e-8f);
            gsum += gw;
            entU  = fmaf(gw, l,      entU);
            conU  = fmaf(gw, c.d2,   conU);
            homU  = fmaf(gw, c.inv,  homU);
            g2    = fmaf(gw, g,      g2);
            siU   = fmaf(gw, c.si,   siU);
            siiU  = fmaf(gw, c.sii,  siiU);
            sijU  = fmaf(gw, c.sij,  sijU);
        }
    }
    // reduce over sub (lanes ^16, ^32) with precomputed bpermute addresses
    const int xa16 = (lane ^ 16) << 2;
    const int xa32 = (lane ^ 32) << 2;
    gsum += bperm_f(xa16, gsum);  entU += bperm_f(xa16, entU);
    conU += bperm_f(xa16, conU);  homU += bperm_f(xa16, homU);
    g2   += bperm_f(xa16, g2);    siU  += bperm_f(xa16, siU);
    siiU += bperm_f(xa16, siiU);  sijU += bperm_f(xa16, sijU);
    gsum += bperm_f(xa32, gsum);  entU += bperm_f(xa32, entU);
    conU += bperm_f(xa32, conU);  homU += bperm_f(xa32, homU);
    g2   += bperm_f(xa32, g2);    siU  += bperm_f(xa32, siU);
    siiU += bperm_f(xa32, siiU);  sijU += bperm_f(xa32, sijU);

    if (fo < NU && sub == 0) {
        const float invg = 1.f / fmaxf(gsum, 1e-12f);
        const float si  = siU  * invg;
        const float sii = siiU * invg;
        const float sij = sijU * invg;
        const float varg = fmaxf(sii - si * si, 0.f);   // == sdi*sdj (symmetric P)
        const float cov  = sij - si * si;
        uf[0][fo] = conU * invg;
        uf[1][fo] = homU * invg;
        uf[2][fo] = sqrtf(g2) * invg;
        uf[3][fo] = (varg < 1e-15f) ? 1.f : cov / fmaxf(varg, 1e-15f);
        uf[4][fo] = -entU;
    }

    // ---- accumulate into partial sets ----
    // ptot: unguarded (adding 0.0 is a no-op). pnz: only the 6 hist features can be
    // legitimately zero with this input; all other features are nonzero iff n>0, so
    // their nz equals the window count, accumulated once per wave into pnz slot (b*NF+0)
    // (feature 0's pnz slot is unused since its count is hardwired too).
    const int setbase = (widx & setmask) * ACC;
    const int obase   = b * NF;
    for (int t = lane; t < NF; t += 64) {
        float f;
        if (t < 10) {
            f = s10[t];
        } else {
            int u    = t - 10;
            int grp  = u / 12;          // 0=contrast 1=homog 2=energy 3=corr 4=entropy
            int slot = u - grp * 12;
            f = uf[grp][c_s2u[slot]];
        }
        atomicAdd(&ptot[setbase + obase + t], f);
        if (t >= 4 && t <= 9 && f != 0.f)
            atomicAdd(&pnz[setbase + obase + t], 1.f);
    }
    if (lane == 0)
        atomicAdd(&pnz[setbase + obase], 1.f);   // window count (n>0 windows)
}

__global__ void reduce_kernel(const float* __restrict__ ptot,
                              const float* __restrict__ pnz,
                              float* __restrict__ out, int nset) {
    int t = blockIdx.x * blockDim.x + threadIdx.x;
    if (t >= ACC) return;
    int b = t / NF;
    int u = t - b * NF;
    bool hist = (u >= 4 && u <= 9);
    int nzidx = hist ? t : b * NF;       // hardwired features use the window count
    float s = 0.f, nz = 0.f;
    for (int k = 0; k < nset; ++k) {
        s  += ptot[(size_t)k * ACC + t];
        nz += pnz[(size_t)k * ACC + nzidx];
    }
    out[t] = s / (nz + 1e-9f);
}

extern "C" void kernel_launch(void* const* d_in, const int* in_sizes, int n_in,
                              void* d_out, int out_size, void* d_ws, size_t ws_size,
                              hipStream_t stream) {
    (void)in_sizes; (void)n_in; (void)out_size;
    const float* x = (const float*)d_in[0];
    float* out = (float*)d_out;

    const size_t per_set = (size_t)2 * ACC * sizeof(float);   // 4480 B
    int maxs = (ws_size >= per_set) ? (int)(ws_size / per_set) : 1;
    int nset = 1;
    while ((nset * 2) <= maxs && nset < 64) nset <<= 1;

    float* ptot = (float*)d_ws;
    float* pnz  = ptot + (size_t)nset * ACC;

    hipMemsetAsync(d_ws, 0, (size_t)nset * per_set, stream);
    feat_kernel<<<dim3(NBLK), dim3(WPB * 64), 0, stream>>>(x, ptot, pnz, nset - 1);
    reduce_kernel<<<dim3((ACC + 255) / 256), dim3(256), 0, stream>>>(ptot, pnz, out, nset);
}